// Round 21
// baseline (10105.274 us; speedup 1.0000x reference)
//
#include <hip/hip_runtime.h>

#define B_ 128
#define T_ 200
#define INF_ 175
#define INFP_ 192
#define H_ 1024
#define G4_ 4096
#define OUTF_ 175
#define BH3_ (3 * B_ * H_)
#define NCELL 192
#define NDEC 22
#define NWORK (NCELL + NDEC)
#define NBLK (NWORK + 1)
#define SP 16
#define AS 69   // cell s_acc row stride (floats)
#define DS 17   // dec reduce stride

typedef __bf16 bf16x8 __attribute__((ext_vector_type(8)));
typedef float f32x4 __attribute__((ext_vector_type(4)));

// ---- persistent device state ----
__device__ __attribute__((aligned(16))) __bf16 g_Wih1p[G4_ * INFP_];
__device__ __attribute__((aligned(16))) __bf16 g_Whh1[G4_ * H_];
__device__ __attribute__((aligned(16))) __bf16 g_Wih2[G4_ * H_];
__device__ __attribute__((aligned(16))) __bf16 g_Whh2[G4_ * H_];
__device__ __attribute__((aligned(16))) __bf16 g_Wih3[G4_ * H_];
__device__ __attribute__((aligned(16))) __bf16 g_Whh3[G4_ * H_];
__device__ __attribute__((aligned(16))) __bf16 g_Wdec[OUTF_ * H_];
__device__ float g_bsum[3 * G4_];
__device__ float g_bdec[OUTF_];
__device__ __attribute__((aligned(16))) __bf16 g_h[2][BH3_];
__device__ __attribute__((aligned(16))) __bf16 g_infp[B_ * INFP_];
__device__ __attribute__((aligned(16))) __bf16 g_xp[(long)T_ * B_ * INFP_];
__device__ int g_isf32;
__device__ int g_flags[256 * SP];
__device__ int g_dflags[32 * SP];
__device__ int g_gen8[8 * SP];
__device__ int g_iready8[8 * SP];

__device__ __forceinline__ f32x4 mfma_bf16(bf16x8 a, bf16x8 b, f32x4 c) {
    return __builtin_amdgcn_mfma_f32_16x16x32_bf16(a, b, c, 0, 0, 0);
}
__device__ __forceinline__ bf16x8 ld8(const __bf16* p) {
    return *reinterpret_cast<const bf16x8*>(p);
}
__device__ __forceinline__ float sigm(float x) { return 1.f / (1.f + expf(-x)); }
__device__ __forceinline__ float rdf(const void* p, long i, int f32) {
    return f32 ? ((const float*)p)[i] : (float)((const __bf16*)p)[i];
}
__device__ __forceinline__ unsigned short bf2u(__bf16 v) {
    union { __bf16 b; unsigned short u; } c; c.b = v; return c.u;
}

// LDS-publish barrier (keeps global prefetch in flight)
__device__ __forceinline__ void lds_barrier() {
    asm volatile("s_waitcnt lgkmcnt(0)" ::: "memory");
    __builtin_amdgcn_s_barrier();
}

// RMW-poll + one acquire at exit. Bounded (hang-proof).
__device__ __forceinline__ void spin_rmw(int* addr, int target, int iters) {
    for (int it = 0; it < iters; ++it) {
        if (__hip_atomic_fetch_max(addr, 0, __ATOMIC_RELAXED, __HIP_MEMORY_SCOPE_AGENT) >= target)
            break;
        __builtin_amdgcn_s_sleep(1);
    }
    (void)__hip_atomic_load(addr, __ATOMIC_ACQUIRE, __HIP_MEMORY_SCOPE_AGENT);
}

// ---- dtype probe ----
__global__ void detect_k(const unsigned int* __restrict__ xw) {
    __shared__ int cnt;
    if (threadIdx.x == 0) cnt = 0;
    __syncthreads();
    unsigned int w = xw[threadIdx.x];
    int e = (w >> 7) & 0xFF;
    if (e >= 140) atomicAdd(&cnt, 1);
    __syncthreads();
    if (threadIdx.x == 0) g_isf32 = (cnt >= 16) ? 1 : 0;
}

// ---- prep ----
__global__ void prep_k(const void* Wih1, const void* Whh1, const void* Wih2,
                       const void* Whh2, const void* Wih3, const void* Whh3,
                       const void* Wdec, const void* bih1, const void* bhh1,
                       const void* bih2, const void* bhh2, const void* bih3,
                       const void* bhh3, const void* bdec, const void* xseq) {
    const int f = g_isf32;
    const int idx = blockIdx.x * 256 + threadIdx.x;
    const int stride = gridDim.x * 256;
    if (idx < 256 * SP) g_flags[idx] = 0;
    if (idx < 32 * SP) g_dflags[idx] = 0;
    if (idx < 8 * SP) { g_gen8[idx] = 0; g_iready8[idx] = 0; }
    for (int i = idx; i < G4_ * INFP_; i += stride) {
        int n = i / INFP_, k = i - n * INFP_;
        g_Wih1p[i] = (k < INF_) ? (__bf16)rdf(Wih1, (long)n * INF_ + k, f) : (__bf16)0.f;
    }
    for (int i = idx; i < G4_ * H_; i += stride) {
        g_Whh1[i] = (__bf16)rdf(Whh1, i, f);
        g_Wih2[i] = (__bf16)rdf(Wih2, i, f);
        g_Whh2[i] = (__bf16)rdf(Whh2, i, f);
        g_Wih3[i] = (__bf16)rdf(Wih3, i, f);
        g_Whh3[i] = (__bf16)rdf(Whh3, i, f);
    }
    for (int i = idx; i < OUTF_ * H_; i += stride) g_Wdec[i] = (__bf16)rdf(Wdec, i, f);
    for (int i = idx; i < G4_; i += stride) {
        g_bsum[i]           = rdf(bih1, i, f) + rdf(bhh1, i, f);
        g_bsum[G4_ + i]     = rdf(bih2, i, f) + rdf(bhh2, i, f);
        g_bsum[2 * G4_ + i] = rdf(bih3, i, f) + rdf(bhh3, i, f);
    }
    for (int i = idx; i < OUTF_; i += stride) g_bdec[i] = rdf(bdec, i, f);
    for (int i = idx; i < 2 * BH3_; i += stride) (&g_h[0][0])[i] = (__bf16)0.f;
    for (int i = idx; i < B_ * INFP_; i += stride) g_infp[i] = (__bf16)0.f;
    const long total = (long)T_ * B_ * INFP_;
    for (long i = idx; i < total; i += stride) {
        int k = (int)(i % INFP_);
        long bt = i / INFP_;
        int b = (int)(bt % B_);
        int t = (int)(bt / B_);
        g_xp[((long)t * B_ + b) * INFP_ + k] =
            (k < INF_) ? (__bf16)rdf(xseq, (long)b * (T_ * INF_) + (long)t * INF_ + k, f)
                       : (__bf16)0.f;
    }
}

// ---- worker barrier (r14, proven) ----
__device__ __forceinline__ void gridbar_w(int bid, int grp, int target) {
    __syncthreads();
    if (threadIdx.x == 0) {
        __threadfence();
        __hip_atomic_fetch_max(&g_flags[bid * SP], target, __ATOMIC_RELAXED, __HIP_MEMORY_SCOPE_AGENT);
        spin_rmw(&g_gen8[grp * SP], target, 4000);
    }
    __syncthreads();
}

// ---- persistent kernel ----
__global__ __launch_bounds__(512, 1) void persist_k(const void* __restrict__ xseq,
                                                    void* __restrict__ dout) {
    __shared__ __attribute__((aligned(16))) char s_tile[2][2][16384];  // 64KB
    __shared__ float s_acc[B_ * AS];   // 35.3KB
    __shared__ float s_c[B_ * 16];     // 8KB
    __shared__ int s_nf, s_nd;
    const int bid = blockIdx.x;
    const int grp = bid & 7;
    const int tid = threadIdx.x;
    const int lane = tid & 63;
    const int wid = tid >> 6;
    const int rlo = lane & 15, khi = lane >> 4;
    const int f32o = g_isf32;
    const int r7l = rlo & 7;
    const int sw0 = (khi ^ r7l) * 16;
    const int sw1 = ((khi + 4) ^ r7l) * 16;

    if (bid < NCELL) {
        // ================= CELL BLOCK =================
        // waves = (op, gate-pair, k-parity). K=1024 weights STREAM from L2/L3
        // (read-only, L3-resident, depth-1 prefetch) -> register file free for
        // acc 64 -> each A-fragment read feeds 2 MFMAs -> LDS A-reads halved.
        const int L = bid >> 6;
        const int hc0 = (bid & 63) << 4;
        const int op = wid >> 2;          // 0: x-GEMM, 1: recurrent GEMM
        const int gp = (wid >> 1) & 1;    // gate pair {2gp, 2gp+1}
        const int kh = wid & 1;           // chunk parity owned
        const float* bs = g_bsum + L * G4_;
        const int XOFF = (L == 0) ? 13 : 0;

        const __bf16* Bm; int K;
        if (op == 0) {
            if (L == 0) { Bm = g_Wih1p; K = INFP_; }
            else        { Bm = (L == 1) ? g_Wih2 : g_Wih3; K = H_; }
        } else {
            Bm = (L == 0) ? g_Whh1 : (L == 1) ? g_Whh2 : g_Whh3; K = H_;
        }
        const bool streamW = (K == H_);
        const __bf16* wpA = Bm + (long)((gp * 2 + 0) * H_ + hc0 + rlo) * K + khi * 8;
        const __bf16* wpB = Bm + (long)((gp * 2 + 1) * H_ + hc0 + rlo) * K + khi * 8;

        // L0 x-waves: K=192 tiny -> persistent frags, ownership by CHUNK parity:
        // kh=0 owns x-chunks 0,2 (q=0,1); kh=1 owns x-chunk 1 (q=0).
        bf16x8 wper[8];
        if (!streamW) {
#pragma unroll
            for (int q = 0; q < 2; ++q) {
                int c = (kh == 0) ? (q * 2) : 1;   // kh1 q=1 duplicates chunk 1 (unused)
                wper[q * 4 + 0] = ld8(wpA + c * 64);
                wper[q * 4 + 1] = ld8(wpA + c * 64 + 32);
                wper[q * 4 + 2] = ld8(wpB + c * 64);
                wper[q * 4 + 3] = ld8(wpB + c * 64 + 32);
            }
        }

        // staging (r14-proven register path)
        const int strow = tid >> 2, stq = tid & 3, str7 = strow & 7;
        auto ldchunk = [&](const __bf16* src, int sA, int k0, bf16x8& v0, bf16x8& v1) {
            const __bf16* pr = src + (long)strow * sA + k0 + stq * 8;
            v0 = ld8(pr);
            v1 = ld8(pr + 32);
        };
        auto wrchunk = [&](char* tile, bf16x8 v0, bf16x8 v1) {
            char* pb = tile + strow * 128;
            *(bf16x8*)(pb + ((stq ^ str7) * 16)) = v0;
            *(bf16x8*)(pb + (((stq + 4) ^ str7) * 16)) = v1;
        };

        for (int i = tid; i < B_ * 16; i += 512) s_c[i] = 0.f;
        __syncthreads();

        for (int p = 0; p < T_; ++p) {
            const bool gt = ((p % 10) < 5);
            const __bf16* hin = g_h[p & 1];
            const __bf16* Apx; int sAx, nx;
            if (L == 0) {
                Apx = gt ? (g_xp + (long)p * B_ * INFP_) : g_infp;
                sAx = INFP_; nx = 3;
            } else {
                Apx = hin + (L - 1) * B_ * H_; sAx = H_; nx = 16;
            }
            const __bf16* Aph = hin + L * B_ * H_;
            const bool needwait = (L == 0) && !gt;

            // W-stream prologue: prefetch first owned chunk's 4 frags (L2/L3-hot)
            bf16x8 wn0, wn1, wn2, wn3;
            if (streamW) {
                wn0 = ld8(wpA + kh * 64);      wn1 = ld8(wpA + kh * 64 + 32);
                wn2 = ld8(wpB + kh * 64);      wn3 = ld8(wpB + kh * 64 + 32);
            }

            // A prologue: stage chunk 0 (h; + x when XOFF==0)
            bf16x8 rx0, rx1, rh0, rh1;
            ldchunk(Aph, H_, 0, rh0, rh1);
            if (XOFF == 0) ldchunk(Apx, sAx, 0, rx0, rx1);
            wrchunk(&s_tile[0][1][0], rh0, rh1);
            if (XOFF == 0) wrchunk(&s_tile[0][0][0], rx0, rx1);
            ldchunk(Aph, H_, 64, rh0, rh1);
            if (XOFF == 0) ldchunk(Apx, sAx, 64, rx0, rx1);
            lds_barrier();

            f32x4 acc[8][2] = {};
            int buf = 0;
#pragma unroll
            for (int i = 0; i < 16; ++i) {
                if (i < 15) wrchunk(&s_tile[buf ^ 1][1][0], rh0, rh1);
                {
                    int xj1 = i + 1 - XOFF;
                    if (xj1 >= 0 && xj1 < nx) wrchunk(&s_tile[buf ^ 1][0][0], rx0, rx1);
                }
                if (i == 11 && needwait) {
                    if (tid == 0) spin_rmw(&g_iready8[grp * SP], p, 3000);
                    __syncthreads();
                }
                if (i < 14) ldchunk(Aph, H_, (i + 2) * 64, rh0, rh1);
                {
                    int xj2 = i + 2 - XOFF;
                    if (xj2 >= 0 && xj2 < nx) ldchunk(Apx, sAx, xj2 * 64, rx0, rx1);
                }
                // compute chunk i (h) / xj (x) if parity matches ownership
                {
                    const char* tb = nullptr;
                    bf16x8 f0, f1, f2, f3;
                    if (op == 1) {
                        if ((i & 1) == kh) {
                            tb = &s_tile[buf][1][0];
                            f0 = wn0; f1 = wn1; f2 = wn2; f3 = wn3;
                            const int cn = (i + 2 <= 15) ? i + 2 : i;
                            wn0 = ld8(wpA + cn * 64); wn1 = ld8(wpA + cn * 64 + 32);
                            wn2 = ld8(wpB + cn * 64); wn3 = ld8(wpB + cn * 64 + 32);
                        }
                    } else {
                        int xj = i - XOFF;
                        if (xj >= 0 && xj < nx && (xj & 1) == kh) {
                            tb = &s_tile[buf][0][0];
                            if (streamW) {   // xj == i here (XOFF=0)
                                f0 = wn0; f1 = wn1; f2 = wn2; f3 = wn3;
                                const int cn = (i + 2 <= 15) ? i + 2 : i;
                                wn0 = ld8(wpA + cn * 64); wn1 = ld8(wpA + cn * 64 + 32);
                                wn2 = ld8(wpB + cn * 64); wn3 = ld8(wpB + cn * 64 + 32);
                            } else {
                                int q = xj >> 1;   // kh0: xj 0,2 -> q 0,1; kh1: xj 1 -> q 0
                                f0 = wper[q * 4 + 0]; f1 = wper[q * 4 + 1];
                                f2 = wper[q * 4 + 2]; f3 = wper[q * 4 + 3];
                            }
                        }
                    }
                    if (tb) {
#pragma unroll
                        for (int mf = 0; mf < 8; ++mf) {
                            const char* rb = tb + (mf * 16 + rlo) * 128;
                            bf16x8 a0 = *(const bf16x8*)(rb + sw0);
                            bf16x8 a1 = *(const bf16x8*)(rb + sw1);
                            acc[mf][0] = mfma_bf16(a0, f0, acc[mf][0]);
                            acc[mf][1] = mfma_bf16(a0, f2, acc[mf][1]);
                            acc[mf][0] = mfma_bf16(a1, f1, acc[mf][0]);
                            acc[mf][1] = mfma_bf16(a1, f3, acc[mf][1]);
                        }
                    }
                }
                lds_barrier();
                buf ^= 1;
            }

            // 4-round partial reduce into s_acc[row][gatecol], AS-padded
#pragma unroll
            for (int rd = 0; rd < 4; ++rd) {
                const int rop = (rd < 2) ? 1 : 0, rkh = rd & 1;
                if (op == rop && kh == rkh) {
#pragma unroll
                    for (int mf = 0; mf < 8; ++mf)
#pragma unroll
                        for (int g01 = 0; g01 < 2; ++g01)
#pragma unroll
                            for (int j = 0; j < 4; ++j) {
                                int r = mf * 16 + khi * 4 + j;
                                int gc = (gp * 2 + g01) * 16 + rlo;
                                if (rd == 0) s_acc[r * AS + gc] = acc[mf][g01][j];
                                else         s_acc[r * AS + gc] += acc[mf][g01][j];
                            }
                }
                __syncthreads();
            }

            // epilogue: 8 waves x 16 rows, 4 cols/lane; h out = NT store
            {
                const int r = wid * 16 + rlo;
                const int hq = khi;
                f32x4 cv = *(const f32x4*)&s_c[r * 16 + hq * 4];
                unsigned long long hbits;
                unsigned short* hp = (unsigned short*)&hbits;
#pragma unroll
                for (int e = 0; e < 4; ++e) {
                    int col = hc0 + hq * 4 + e;
                    float gi_ = s_acc[r * AS + 0 * 16 + hq * 4 + e] + bs[0 * H_ + col];
                    float gf_ = s_acc[r * AS + 1 * 16 + hq * 4 + e] + bs[1 * H_ + col];
                    float gg_ = s_acc[r * AS + 2 * 16 + hq * 4 + e] + bs[2 * H_ + col];
                    float go_ = s_acc[r * AS + 3 * 16 + hq * 4 + e] + bs[3 * H_ + col];
                    float cn = sigm(gf_) * cv[e] + sigm(gi_) * tanhf(gg_);
                    cv[e] = cn;
                    hp[e] = bf2u((__bf16)(sigm(go_) * tanhf(cn)));
                }
                *(f32x4*)&s_c[r * 16 + hq * 4] = cv;
                __bf16* hdst = g_h[(p + 1) & 1] + L * B_ * H_ + r * H_ + hc0 + hq * 4;
                __builtin_nontemporal_store(hbits, (unsigned long long*)hdst);
            }
            gridbar_w(bid, grp, p + 1);
        }
    } else if (bid < NWORK) {
        // ================= DEC BLOCK (r14, unchanged) =================
        const int db = bid - NCELL;
        const int ntile = db % 11, mh = db / 11;
        const int kk = wid >> 2;
        const int mw = wid & 3;
        const int col = ntile * 16 + rlo;
        const int colc = (col < OUTF_) ? col : (OUTF_ - 1);

        const __bf16* pb = g_Wdec + (long)colc * H_ + khi * 8;
        bf16x8 dw[16];
#pragma unroll
        for (int c = 0; c < 16; ++c) dw[c] = ld8(pb + (kk * 16 + c) * 32);

        const int strow = tid >> 3, stc8 = tid & 7, str7 = strow & 7;
        char* const dt0 = &s_tile[0][0][0];
        char* const dt1 = &s_tile[1][0][0];

        auto decwork = [&](int t, bool winf) {
            const bool gtn = (((t + 1) % 10) < 5);
            const __bf16* h2 = g_h[(t + 1) & 1] + 2 * B_ * H_;
            const __bf16* hrow = h2 + (long)(mh * 64 + strow) * H_ + stc8 * 8;
            bf16x8 rv = ld8(hrow);
            *(bf16x8*)(dt0 + strow * 128 + ((stc8 ^ str7) * 16)) = rv;
            rv = ld8(hrow + 64);
            lds_barrier();
            f32x4 acc = {};
            int b = 0;
#pragma unroll
            for (int i = 0; i < 16; ++i) {
                if (i < 15) *(bf16x8*)((b ? dt0 : dt1) + strow * 128 + ((stc8 ^ str7) * 16)) = rv;
                if (i < 14) rv = ld8(hrow + (i + 2) * 64);
                {
                    const char* rb = (b ? dt1 : dt0) + (mw * 16 + rlo) * 128;
                    bf16x8 a0 = *(const bf16x8*)(rb + sw0);
                    bf16x8 a1 = *(const bf16x8*)(rb + sw1);
                    if (i < 8) {
                        if (kk == 0) {
                            acc = mfma_bf16(a0, dw[2 * i], acc);
                            acc = mfma_bf16(a1, dw[2 * i + 1], acc);
                        }
                    } else {
                        if (kk == 1) {
                            acc = mfma_bf16(a0, dw[2 * i - 16], acc);
                            acc = mfma_bf16(a1, dw[2 * i - 15], acc);
                        }
                    }
                }
                lds_barrier();
                b ^= 1;
            }
            if (kk == 1) {
#pragma unroll
                for (int j = 0; j < 4; ++j)
                    s_acc[(mw * 16 + khi * 4 + j) * DS + rlo] = acc[j];
            }
            __syncthreads();
            if (kk == 0) {
#pragma unroll
                for (int j = 0; j < 4; ++j)
                    acc[j] += s_acc[(mw * 16 + khi * 4 + j) * DS + rlo];
                if (col < OUTF_) {
                    const float bias = g_bdec[col];
#pragma unroll
                    for (int j = 0; j < 4; ++j) {
                        int row = mh * 64 + mw * 16 + khi * 4 + j;
                        float ov = acc[j] + bias;
                        long oidx = (long)row * (T_ * OUTF_) + (long)t * OUTF_ + col;
                        if (f32o) __builtin_nontemporal_store(ov, (float*)dout + oidx);
                        else __builtin_nontemporal_store(bf2u((__bf16)ov), (unsigned short*)dout + oidx);
                        if (winf && !gtn) {
                            __builtin_nontemporal_store(bf2u((__bf16)ov),
                                (unsigned short*)g_infp + row * INFP_ + col);
                        }
                    }
                }
            }
            __syncthreads();
            if (tid == 0) {
                __threadfence();
                __hip_atomic_fetch_max(&g_dflags[db * SP], t + 1, __ATOMIC_RELAXED, __HIP_MEMORY_SCOPE_AGENT);
            }
        };

        for (int p = 0; p < T_; ++p) {
            if (p >= 1) decwork(p - 1, true);
            gridbar_w(bid, grp, p + 1);
        }
        decwork(T_ - 1, false);
    } else {
        // ======== MASTER BLOCK (r11, proven) ========
        for (int p = 0; p < T_; ++p) {
            const int tgt = p + 1;
            bool ir_done = false;
            for (int it = 0; it < 2000; ++it) {
                if (tid == 0) { s_nf = 0; s_nd = 0; }
                __syncthreads();
                int bad_f = 0, bad_d = 0;
                if (tid < NWORK)
                    bad_f = (__hip_atomic_fetch_max(&g_flags[tid * SP], 0, __ATOMIC_RELAXED, __HIP_MEMORY_SCOPE_AGENT) < tgt);
                if (!ir_done && tid < NDEC)
                    bad_d = (__hip_atomic_fetch_max(&g_dflags[tid * SP], 0, __ATOMIC_RELAXED, __HIP_MEMORY_SCOPE_AGENT) < p);
                if (bad_f) s_nf = 1;
                if (bad_d) s_nd = 1;
                __syncthreads();
                if (!ir_done && !s_nd) {
                    if (tid < 8)
                        __hip_atomic_fetch_max(&g_iready8[tid * SP], p, __ATOMIC_RELAXED, __HIP_MEMORY_SCOPE_AGENT);
                    ir_done = true;
                }
                if (!s_nf) break;
                __builtin_amdgcn_s_sleep(1);
            }
            if (!ir_done && tid < 8)
                __hip_atomic_fetch_max(&g_iready8[tid * SP], p, __ATOMIC_RELAXED, __HIP_MEMORY_SCOPE_AGENT);
            __syncthreads();
            if (tid < 8)
                __hip_atomic_fetch_max(&g_gen8[tid * SP], tgt, __ATOMIC_RELAXED, __HIP_MEMORY_SCOPE_AGENT);
        }
    }
}

extern "C" void kernel_launch(void* const* d_in, const int* in_sizes, int n_in,
                              void* d_out, int out_size, void* d_ws, size_t ws_size,
                              hipStream_t stream) {
    const void* xseq = d_in[0];
    detect_k<<<1, 256, 0, stream>>>((const unsigned int*)xseq);
    prep_k<<<2048, 256, 0, stream>>>(d_in[1], d_in[2], d_in[5], d_in[6], d_in[9],
                                     d_in[10], d_in[13], d_in[3], d_in[4], d_in[7],
                                     d_in[8], d_in[11], d_in[12], d_in[14], xseq);
    persist_k<<<NBLK, 512, 0, stream>>>(xseq, d_out);
}

// Round 22
// 6083.603 us; speedup vs baseline: 1.6611x; 1.6611x over previous
//
#include <hip/hip_runtime.h>

#define B_ 128
#define T_ 200
#define INF_ 175
#define INFP_ 192
#define H_ 1024
#define G4_ 4096
#define OUTF_ 175
#define BH3_ (3 * B_ * H_)
#define NCELL 192
#define NDEC 22
#define NWORK (NCELL + NDEC)
#define NBLK (NWORK + 1)
#define SP 16

typedef __bf16 bf16x8 __attribute__((ext_vector_type(8)));
typedef float f32x4 __attribute__((ext_vector_type(4)));

// ---- persistent device state ----
__device__ __attribute__((aligned(16))) __bf16 g_Wih1p[G4_ * INFP_];
__device__ __attribute__((aligned(16))) __bf16 g_Whh1[G4_ * H_];
__device__ __attribute__((aligned(16))) __bf16 g_Wih2[G4_ * H_];
__device__ __attribute__((aligned(16))) __bf16 g_Whh2[G4_ * H_];
__device__ __attribute__((aligned(16))) __bf16 g_Wih3[G4_ * H_];
__device__ __attribute__((aligned(16))) __bf16 g_Whh3[G4_ * H_];
__device__ __attribute__((aligned(16))) __bf16 g_Wdec[OUTF_ * H_];
__device__ float g_bsum[3 * G4_];
__device__ float g_bdec[OUTF_];
__device__ __attribute__((aligned(16))) __bf16 g_h[2][BH3_];
__device__ __attribute__((aligned(16))) __bf16 g_infp[B_ * INFP_];
__device__ __attribute__((aligned(16))) __bf16 g_xp[(long)T_ * B_ * INFP_]; // padded bf16 xseq
__device__ int g_isf32;
__device__ int g_flags[256 * SP];
__device__ int g_dflags[32 * SP];
__device__ int g_gen8[8 * SP];
__device__ int g_iready8[8 * SP];

__device__ __forceinline__ f32x4 mfma_bf16(bf16x8 a, bf16x8 b, f32x4 c) {
    return __builtin_amdgcn_mfma_f32_16x16x32_bf16(a, b, c, 0, 0, 0);
}
__device__ __forceinline__ bf16x8 ld8(const __bf16* p) {
    return *reinterpret_cast<const bf16x8*>(p);
}
__device__ __forceinline__ float sigm(float x) { return 1.f / (1.f + expf(-x)); }
__device__ __forceinline__ float rdf(const void* p, long i, int f32) {
    return f32 ? ((const float*)p)[i] : (float)((const __bf16*)p)[i];
}
__device__ __forceinline__ unsigned short bf2u(__bf16 v) {
    union { __bf16 b; unsigned short u; } c; c.b = v; return c.u;
}

// LDS-publish barrier that does NOT drain vmcnt: my ds ops complete
// (lgkmcnt 0), then raw s_barrier. Global prefetches stay in flight across it.
__device__ __forceinline__ void lds_barrier() {
    asm volatile("s_waitcnt lgkmcnt(0)" ::: "memory");
    __builtin_amdgcn_s_barrier();
}

// RMW-poll at L3 coherence point + one acquire at exit. Bounded (hang-proof).
__device__ __forceinline__ void spin_rmw(int* addr, int target, int iters) {
    for (int it = 0; it < iters; ++it) {
        if (__hip_atomic_fetch_max(addr, 0, __ATOMIC_RELAXED, __HIP_MEMORY_SCOPE_AGENT) >= target)
            break;
        __builtin_amdgcn_s_sleep(1);
    }
    (void)__hip_atomic_load(addr, __ATOMIC_ACQUIRE, __HIP_MEMORY_SCOPE_AGENT);
}

// ---- dtype probe ----
__global__ void detect_k(const unsigned int* __restrict__ xw) {
    __shared__ int cnt;
    if (threadIdx.x == 0) cnt = 0;
    __syncthreads();
    unsigned int w = xw[threadIdx.x];
    int e = (w >> 7) & 0xFF;
    if (e >= 140) atomicAdd(&cnt, 1);
    __syncthreads();
    if (threadIdx.x == 0) g_isf32 = (cnt >= 16) ? 1 : 0;
}

// ---- prep ----
__global__ void prep_k(const void* Wih1, const void* Whh1, const void* Wih2,
                       const void* Whh2, const void* Wih3, const void* Whh3,
                       const void* Wdec, const void* bih1, const void* bhh1,
                       const void* bih2, const void* bhh2, const void* bih3,
                       const void* bhh3, const void* bdec, const void* xseq) {
    const int f = g_isf32;
    const int idx = blockIdx.x * 256 + threadIdx.x;
    const int stride = gridDim.x * 256;
    if (idx < 256 * SP) g_flags[idx] = 0;
    if (idx < 32 * SP) g_dflags[idx] = 0;
    if (idx < 8 * SP) { g_gen8[idx] = 0; g_iready8[idx] = 0; }
    for (int i = idx; i < G4_ * INFP_; i += stride) {
        int n = i / INFP_, k = i - n * INFP_;
        g_Wih1p[i] = (k < INF_) ? (__bf16)rdf(Wih1, (long)n * INF_ + k, f) : (__bf16)0.f;
    }
    for (int i = idx; i < G4_ * H_; i += stride) {
        g_Whh1[i] = (__bf16)rdf(Whh1, i, f);
        g_Wih2[i] = (__bf16)rdf(Wih2, i, f);
        g_Whh2[i] = (__bf16)rdf(Whh2, i, f);
        g_Wih3[i] = (__bf16)rdf(Wih3, i, f);
        g_Whh3[i] = (__bf16)rdf(Whh3, i, f);
    }
    for (int i = idx; i < OUTF_ * H_; i += stride) g_Wdec[i] = (__bf16)rdf(Wdec, i, f);
    for (int i = idx; i < G4_; i += stride) {
        g_bsum[i]           = rdf(bih1, i, f) + rdf(bhh1, i, f);
        g_bsum[G4_ + i]     = rdf(bih2, i, f) + rdf(bhh2, i, f);
        g_bsum[2 * G4_ + i] = rdf(bih3, i, f) + rdf(bhh3, i, f);
    }
    for (int i = idx; i < OUTF_; i += stride) g_bdec[i] = rdf(bdec, i, f);
    for (int i = idx; i < 2 * BH3_; i += stride) (&g_h[0][0])[i] = (__bf16)0.f;
    for (int i = idx; i < B_ * INFP_; i += stride) g_infp[i] = (__bf16)0.f;
    const long total = (long)T_ * B_ * INFP_;
    for (long i = idx; i < total; i += stride) {
        int k = (int)(i % INFP_);
        long bt = i / INFP_;
        int b = (int)(bt % B_);
        int t = (int)(bt / B_);
        g_xp[((long)t * B_ + b) * INFP_ + k] =
            (k < INF_) ? (__bf16)rdf(xseq, (long)b * (T_ * INF_) + (long)t * INF_ + k, f)
                       : (__bf16)0.f;
    }
}

// ---- worker barrier (proven) ----
__device__ __forceinline__ void gridbar_w(int bid, int grp, int target) {
    __syncthreads();
    if (threadIdx.x == 0) {
        __threadfence();
        __hip_atomic_fetch_max(&g_flags[bid * SP], target, __ATOMIC_RELAXED, __HIP_MEMORY_SCOPE_AGENT);
        spin_rmw(&g_gen8[grp * SP], target, 4000);
    }
    __syncthreads();
}

// ---- persistent kernel ----
__global__ __launch_bounds__(512, 1) void persist_k(const void* __restrict__ xseq,
                                                    void* __restrict__ dout) {
    __shared__ char s_tile[2][2][16384];   // [buf][op][128 rows x 64 cols bf16] 64KB
    __shared__ float s_acc[B_ * 4 * 16];   // 32KB
    __shared__ float s_c[B_ * 16];         // 8KB
    __shared__ int s_nf, s_nd;
    const int bid = blockIdx.x;
    const int grp = bid & 7;
    const int tid = threadIdx.x;
    const int lane = tid & 63;
    const int wid = tid >> 6;
    const int rlo = lane & 15, khi = lane >> 4;
    const int f32o = g_isf32;
    const int r7l = rlo & 7;
    const int sw0 = (khi ^ r7l) * 16;
    const int sw1 = ((khi + 4) ^ r7l) * 16;

    if (bid < NCELL) {
        // ================= CELL BLOCK =================
        const int L = bid >> 6;
        const int hc0 = (bid & 63) << 4;
        const int op = wid >> 2;         // 0: x-GEMM, 1: recurrent GEMM
        const int g = wid & 3;           // gate
        const float* bs = g_bsum + L * G4_;
        const int XOFF = (L == 0) ? 13 : 0;   // L0 x-chunks run at loop idx 13..15

        const __bf16* Bm; int K;
        if (op == 0) {
            if (L == 0) { Bm = g_Wih1p; K = INFP_; }
            else        { Bm = (L == 1) ? g_Wih2 : g_Wih3; K = H_; }
        } else {
            Bm = (L == 0) ? g_Whh1 : (L == 1) ? g_Whh2 : g_Whh3; K = H_;
        }
        const __bf16* wp = Bm + (long)(g * H_ + hc0 + rlo) * K + khi * 8;
        bf16x8 wreg[32];
        if (K == INFP_) {
#pragma unroll
            for (int c = 0; c < 6; ++c) wreg[c] = ld8(wp + c * 32);
        } else {
#pragma unroll
            for (int c = 0; c < 32; ++c) wreg[c] = ld8(wp + c * 32);
        }

        const int strow = tid >> 2, stq = tid & 3, str7 = strow & 7;
        auto ldchunk = [&](const __bf16* src, int sA, int k0, bf16x8& v0, bf16x8& v1) {
            const __bf16* pr = src + (long)strow * sA + k0 + stq * 8;
            v0 = ld8(pr);
            v1 = ld8(pr + 32);
        };
        auto wrchunk = [&](char* tile, bf16x8 v0, bf16x8 v1) {
            char* pb = tile + strow * 128;
            *(bf16x8*)(pb + ((stq ^ str7) * 16)) = v0;
            *(bf16x8*)(pb + (((stq + 4) ^ str7) * 16)) = v1;
        };

        for (int i = tid; i < B_ * 16; i += 512) s_c[i] = 0.f;
        __syncthreads();

        for (int p = 0; p < T_; ++p) {
            const bool gt = ((p % 10) < 5);
            const __bf16* hin = g_h[p & 1];
            const __bf16* Apx; int sAx, nx;
            if (L == 0) {
                Apx = gt ? (g_xp + (long)p * B_ * INFP_) : g_infp;
                sAx = INFP_; nx = 3;
            } else {
                Apx = hin + (L - 1) * B_ * H_; sAx = H_; nx = 16;
            }
            const __bf16* Aph = hin + L * B_ * H_;
            const bool needwait = (L == 0) && !gt;

            // prologue: stage h chunk 0 (+ x chunk 0 when XOFF==0)
            bf16x8 rx0, rx1, rh0, rh1;
            ldchunk(Aph, H_, 0, rh0, rh1);
            if (XOFF == 0) ldchunk(Apx, sAx, 0, rx0, rx1);
            wrchunk(&s_tile[0][1][0], rh0, rh1);
            if (XOFF == 0) wrchunk(&s_tile[0][0][0], rx0, rx1);
            ldchunk(Aph, H_, 64, rh0, rh1);
            if (XOFF == 0) ldchunk(Apx, sAx, 64, rx0, rx1);
            lds_barrier();

            f32x4 acc[8] = {};
            int buf = 0;
#pragma unroll
            for (int i = 0; i < 16; ++i) {
                if (i < 15) wrchunk(&s_tile[buf ^ 1][1][0], rh0, rh1);
                {
                    int xj = i + 1 - XOFF;
                    if (xj >= 0 && xj < nx) wrchunk(&s_tile[buf ^ 1][0][0], rx0, rx1);
                }
                if (i == 11 && needwait) {
                    if (tid == 0) spin_rmw(&g_iready8[grp * SP], p, 3000);
                    __syncthreads();
                }
                if (i < 14) ldchunk(Aph, H_, (i + 2) * 64, rh0, rh1);
                {
                    int xj = i + 2 - XOFF;
                    if (xj >= 0 && xj < nx) ldchunk(Apx, sAx, xj * 64, rx0, rx1);
                }
                if (op == 1) {
                    const char* tb = &s_tile[buf][1][0];
#pragma unroll
                    for (int mf = 0; mf < 8; ++mf) {
                        const char* rb = tb + (mf * 16 + rlo) * 128;
                        acc[mf] = mfma_bf16(*(const bf16x8*)(rb + sw0), wreg[2 * i], acc[mf]);
                        acc[mf] = mfma_bf16(*(const bf16x8*)(rb + sw1), wreg[2 * i + 1], acc[mf]);
                    }
                } else {
                    int xj = i - XOFF;
                    if (xj >= 0 && xj < nx) {
                        const char* tb = &s_tile[buf][0][0];
#pragma unroll
                        for (int mf = 0; mf < 8; ++mf) {
                            const char* rb = tb + (mf * 16 + rlo) * 128;
                            acc[mf] = mfma_bf16(*(const bf16x8*)(rb + sw0), wreg[2 * xj], acc[mf]);
                            acc[mf] = mfma_bf16(*(const bf16x8*)(rb + sw1), wreg[2 * xj + 1], acc[mf]);
                        }
                    }
                }
                lds_barrier();
                buf ^= 1;
            }

            // operand-split reduce through LDS
            if (op == 1) {
#pragma unroll
                for (int mf = 0; mf < 8; ++mf)
#pragma unroll
                    for (int j = 0; j < 4; ++j) {
                        int r = mf * 16 + khi * 4 + j;
                        s_acc[(r * 4 + g) * 16 + rlo] = acc[mf][j];
                    }
            }
            __syncthreads();
            if (op == 0) {
#pragma unroll
                for (int mf = 0; mf < 8; ++mf)
#pragma unroll
                    for (int j = 0; j < 4; ++j) {
                        int r = mf * 16 + khi * 4 + j;
                        s_acc[(r * 4 + g) * 16 + rlo] += acc[mf][j];
                    }
            }
            __syncthreads();

            // epilogue: 8 waves x 16 rows, 4 cols/lane; h out = NT store
            {
                const int r = wid * 16 + rlo;
                const int hq = khi;
                f32x4 ga = *(const f32x4*)&s_acc[(r * 4 + 0) * 16 + hq * 4];
                f32x4 gf = *(const f32x4*)&s_acc[(r * 4 + 1) * 16 + hq * 4];
                f32x4 gg = *(const f32x4*)&s_acc[(r * 4 + 2) * 16 + hq * 4];
                f32x4 go = *(const f32x4*)&s_acc[(r * 4 + 3) * 16 + hq * 4];
                f32x4 cv = *(const f32x4*)&s_c[r * 16 + hq * 4];
                unsigned long long hbits;
                unsigned short* hp = (unsigned short*)&hbits;
#pragma unroll
                for (int e = 0; e < 4; ++e) {
                    int col = hc0 + hq * 4 + e;
                    float gi_ = ga[e] + bs[0 * H_ + col];
                    float gf_ = gf[e] + bs[1 * H_ + col];
                    float gg_ = gg[e] + bs[2 * H_ + col];
                    float go_ = go[e] + bs[3 * H_ + col];
                    float cn = sigm(gf_) * cv[e] + sigm(gi_) * tanhf(gg_);
                    cv[e] = cn;
                    hp[e] = bf2u((__bf16)(sigm(go_) * tanhf(cn)));
                }
                *(f32x4*)&s_c[r * 16 + hq * 4] = cv;
                __bf16* hdst = g_h[(p + 1) & 1] + L * B_ * H_ + r * H_ + hc0 + hq * 4;
                __builtin_nontemporal_store(hbits, (unsigned long long*)hdst);
            }
            gridbar_w(bid, grp, p + 1);
        }
    } else if (bid < NWORK) {
        // ================= DEC BLOCK =================
        const int db = bid - NCELL;
        const int ntile = db % 11, mh = db / 11;
        const int kk = wid >> 2;
        const int mw = wid & 3;
        const int col = ntile * 16 + rlo;
        const int colc = (col < OUTF_) ? col : (OUTF_ - 1);

        const __bf16* pb = g_Wdec + (long)colc * H_ + khi * 8;
        bf16x8 dw[16];
#pragma unroll
        for (int c = 0; c < 16; ++c) dw[c] = ld8(pb + (kk * 16 + c) * 32);

        const int strow = tid >> 3, stc8 = tid & 7, str7 = strow & 7;
        char* const dt0 = &s_tile[0][0][0];
        char* const dt1 = &s_tile[1][0][0];

        auto decwork = [&](int t, bool winf) {
            const bool gtn = (((t + 1) % 10) < 5);
            const __bf16* h2 = g_h[(t + 1) & 1] + 2 * B_ * H_;
            const __bf16* hrow = h2 + (long)(mh * 64 + strow) * H_ + stc8 * 8;
            bf16x8 rv = ld8(hrow);
            *(bf16x8*)(dt0 + strow * 128 + ((stc8 ^ str7) * 16)) = rv;
            rv = ld8(hrow + 64);
            lds_barrier();
            f32x4 acc = {};
            int b = 0;
#pragma unroll
            for (int i = 0; i < 16; ++i) {
                if (i < 15) *(bf16x8*)((b ? dt0 : dt1) + strow * 128 + ((stc8 ^ str7) * 16)) = rv;
                if (i < 14) rv = ld8(hrow + (i + 2) * 64);
                {
                    const char* rb = (b ? dt1 : dt0) + (mw * 16 + rlo) * 128;
                    bf16x8 a0 = *(const bf16x8*)(rb + sw0);
                    bf16x8 a1 = *(const bf16x8*)(rb + sw1);
                    if (i < 8) {
                        if (kk == 0) {
                            acc = mfma_bf16(a0, dw[2 * i], acc);
                            acc = mfma_bf16(a1, dw[2 * i + 1], acc);
                        }
                    } else {
                        if (kk == 1) {
                            acc = mfma_bf16(a0, dw[2 * i - 16], acc);
                            acc = mfma_bf16(a1, dw[2 * i - 15], acc);
                        }
                    }
                }
                lds_barrier();
                b ^= 1;
            }
            if (kk == 1) {
#pragma unroll
                for (int j = 0; j < 4; ++j)
                    s_acc[(mw * 16 + khi * 4 + j) * 16 + rlo] = acc[j];
            }
            __syncthreads();
            if (kk == 0) {
#pragma unroll
                for (int j = 0; j < 4; ++j)
                    acc[j] += s_acc[(mw * 16 + khi * 4 + j) * 16 + rlo];
                if (col < OUTF_) {
                    const float bias = g_bdec[col];
#pragma unroll
                    for (int j = 0; j < 4; ++j) {
                        int row = mh * 64 + mw * 16 + khi * 4 + j;
                        float ov = acc[j] + bias;
                        long oidx = (long)row * (T_ * OUTF_) + (long)t * OUTF_ + col;
                        if (f32o) __builtin_nontemporal_store(ov, (float*)dout + oidx);
                        else __builtin_nontemporal_store(bf2u((__bf16)ov), (unsigned short*)dout + oidx);
                        if (winf && !gtn) {
                            __builtin_nontemporal_store(bf2u((__bf16)ov),
                                (unsigned short*)g_infp + row * INFP_ + col);
                        }
                    }
                }
            }
            __syncthreads();
            if (tid == 0) {
                __threadfence();
                __hip_atomic_fetch_max(&g_dflags[db * SP], t + 1, __ATOMIC_RELAXED, __HIP_MEMORY_SCOPE_AGENT);
            }
        };

        for (int p = 0; p < T_; ++p) {
            if (p >= 1) decwork(p - 1, true);
            gridbar_w(bid, grp, p + 1);
        }
        decwork(T_ - 1, false);
    } else {
        // ======== MASTER BLOCK ========
        for (int p = 0; p < T_; ++p) {
            const int tgt = p + 1;
            bool ir_done = false;
            for (int it = 0; it < 2000; ++it) {
                if (tid == 0) { s_nf = 0; s_nd = 0; }
                __syncthreads();
                int bad_f = 0, bad_d = 0;
                if (tid < NWORK)
                    bad_f = (__hip_atomic_fetch_max(&g_flags[tid * SP], 0, __ATOMIC_RELAXED, __HIP_MEMORY_SCOPE_AGENT) < tgt);
                if (!ir_done && tid < NDEC)
                    bad_d = (__hip_atomic_fetch_max(&g_dflags[tid * SP], 0, __ATOMIC_RELAXED, __HIP_MEMORY_SCOPE_AGENT) < p);
                if (bad_f) s_nf = 1;
                if (bad_d) s_nd = 1;
                __syncthreads();
                if (!ir_done && !s_nd) {
                    if (tid < 8)
                        __hip_atomic_fetch_max(&g_iready8[tid * SP], p, __ATOMIC_RELAXED, __HIP_MEMORY_SCOPE_AGENT);
                    ir_done = true;
                }
                if (!s_nf) break;
                __builtin_amdgcn_s_sleep(1);
            }
            if (!ir_done && tid < 8)
                __hip_atomic_fetch_max(&g_iready8[tid * SP], p, __ATOMIC_RELAXED, __HIP_MEMORY_SCOPE_AGENT);
            __syncthreads();
            if (tid < 8)
                __hip_atomic_fetch_max(&g_gen8[tid * SP], tgt, __ATOMIC_RELAXED, __HIP_MEMORY_SCOPE_AGENT);
        }
    }
}

extern "C" void kernel_launch(void* const* d_in, const int* in_sizes, int n_in,
                              void* d_out, int out_size, void* d_ws, size_t ws_size,
                              hipStream_t stream) {
    const void* xseq = d_in[0];
    detect_k<<<1, 256, 0, stream>>>((const unsigned int*)xseq);
    prep_k<<<2048, 256, 0, stream>>>(d_in[1], d_in[2], d_in[5], d_in[6], d_in[9],
                                     d_in[10], d_in[13], d_in[3], d_in[4], d_in[7],
                                     d_in[8], d_in[11], d_in[12], d_in[14], xseq);
    persist_k<<<NBLK, 512, 0, stream>>>(xseq, d_out);
}